// Round 5
// baseline (2059.245 us; speedup 1.0000x reference)
//
#include <hip/hip_runtime.h>
#include <hip/hip_bf16.h>
#include <math.h>

#define BB 8
#define TT 4096
#define CC 512
#define BT (BB*TT)
#define KD 256
#define VD 512
#define NSUB 128
#define SUB 32

using bf16 = __hip_bfloat16;
typedef __attribute__((ext_vector_type(4))) float f32x4;
typedef __attribute__((ext_vector_type(8))) short s16x8;
typedef __attribute__((ext_vector_type(8))) unsigned short u16x8;
typedef const __attribute__((address_space(1))) unsigned int gu32;
typedef __attribute__((address_space(3))) unsigned int lu32;

static __device__ __forceinline__ float bf2f(bf16 x){ return __bfloat162float(x); }
static __device__ __forceinline__ bf16 f2bf(float x){ return __float2bfloat16(x); }
static __device__ __forceinline__ float bfbits(unsigned short u){
  union { unsigned int i; float f; } x; x.i = ((unsigned int)u)<<16; return x.f;
}
static __device__ __forceinline__ unsigned short f2bfbits(float f){
  union { bf16 b; unsigned short u; } x; x.b = f2bf(f); return x.u;
}
static __device__ __forceinline__ void gload16(const void* g, void* l){
  __builtin_amdgcn_global_load_lds((gu32*)g, (lu32*)l, 16, 0, 0);
}

// ---------------- workspace arena (bytes), peak ~217.3 MiB; Mseg lives in d_out ----------------
#define MiB 1048576ull
static constexpr size_t OFF_H1   = 0;           // bf16 BT*C (32)  ; p3 out GATED ; FFN RF
static constexpr size_t OFF_XX   = 32*MiB;      // bf16 BT*256 (16); dead by scan
static constexpr size_t OFF_DSEG = 32*MiB;      // f32 4096*64 (1) alias XX
static constexpr size_t OFF_HM   = 48*MiB;      // bf16 BT*C (32)  ; FFN HN
static constexpr size_t OFF_R    = 80*MiB;      // bf16 BT*256 (16); FFN KIN (spans R+K)
static constexpr size_t OFF_K    = 96*MiB;      // bf16 BT*256 (16)
static constexpr size_t OFF_V    = 112*MiB;     // bf16 BT*512 (32); FFN RIN
static constexpr size_t OFF_WD   = 144*MiB;     // f32 BT*256 (32) ; FFN KF low
static constexpr size_t OFF_G    = 176*MiB;     // bf16 BT*512 (32); FFN KF high
static constexpr size_t OFF_W1T  = 208*MiB;     // bf16 BT*64 (4)
static constexpr size_t WT_X1  = 212*MiB;            // 512x256 bf16
static constexpr size_t WT_R   = WT_X1  + 262144;
static constexpr size_t WT_K   = WT_R   + 262144;
static constexpr size_t WT_V   = WT_K   + 262144;
static constexpr size_t WT_G   = WT_V   + 524288;
static constexpr size_t WT_W1  = WT_G   + 524288;
static constexpr size_t WT_W2  = WT_W1  + 65536;
static constexpr size_t WT_O   = WT_W2  + 32768;
static constexpr size_t WT_KEY = WT_O   + 524288;
static constexpr size_t WT_REC = WT_KEY + 1048576;
static constexpr size_t WT_VAL = WT_REC + 524288;
static constexpr size_t WS_NEED = WT_VAL + 1048576;

// ---------------- fused weight convert+transpose for all 11 weights ----------------
__global__ void wconv_all(const float* s0, const float* s1, const float* s2, const float* s3,
                          const float* s4, const float* s5, const float* s6, const float* s7,
                          const float* s8, const float* s9, const float* s10, char* ws){
  struct E{int K,N,Npad; size_t off;};
  const E tab[11] = {
    {512,160,256,WT_X1},{512,256,256,WT_R},{512,256,256,WT_K},{512,512,512,WT_V},
    {512,512,512,WT_G},{512,64,64,WT_W1},{64,256,256,WT_W2},{512,512,512,WT_O},
    {512,1024,1024,WT_KEY},{512,512,512,WT_REC},{1024,512,512,WT_VAL}};
  const float* srcs[11] = {s0,s1,s2,s3,s4,s5,s6,s7,s8,s9,s10};
  int blk = blockIdx.x, i = 0, acc = 0;
  #pragma unroll 1
  for (; i<11; i++){ int nb = tab[i].K*tab[i].Npad/256; if (blk < acc+nb) break; acc += nb; }
  int idx = (blk-acc)*256 + threadIdx.x;
  int K = tab[i].K, N = tab[i].N;
  int n = idx / K, k = idx - n*K;
  float v = (n < N) ? srcs[i][(size_t)k*N + n] : 0.f;
  ((bf16*)(ws + tab[i].off))[idx] = f2bf(v);
}

// ---------------- LayerNorm over C=512, block per row, bf16 out ----------------
__global__ __launch_bounds__(256) void ln_bf16(const float* __restrict__ x, const float* __restrict__ w,
                                               const float* __restrict__ b, bf16* __restrict__ out){
  int bt = blockIdx.x;
  const float* row = x + (size_t)bt*CC;
  int t = threadIdx.x;
  float a0 = row[t], a1 = row[t+256];
  float s = a0 + a1, ss = a0*a0 + a1*a1;
  for (int off=32; off; off>>=1){ s += __shfl_down(s, off, 64); ss += __shfl_down(ss, off, 64); }
  __shared__ float ps[4], pss[4];
  int wv = t>>6, ln = t&63;
  if (ln==0){ ps[wv]=s; pss[wv]=ss; }
  __syncthreads();
  if (t==0){
    float S=ps[0]+ps[1]+ps[2]+ps[3], SS=pss[0]+pss[1]+pss[2]+pss[3];
    float mu = S/CC; float var = SS/CC - mu*mu;
    ps[0]=mu; pss[0]=rsqrtf(var+1e-5f);
  }
  __syncthreads();
  float mu = ps[0], inv = pss[0];
  out[(size_t)bt*CC + t]     = f2bf((a0-mu)*inv*w[t]+b[t]);
  out[(size_t)bt*CC + t+256] = f2bf((a1-mu)*inv*w[t+256]+b[t+256]);
}

// ---------------- xm = h + (shift(h)-h)*mu_x  (bf16 in/out) ----------------
__global__ void build_xm(const bf16* __restrict__ h, const float* __restrict__ mu_x, bf16* __restrict__ xm){
  size_t idx = (size_t)blockIdx.x*256 + threadIdx.x;
  int c = (int)(idx & (CC-1));
  size_t bt = idx >> 9;
  float hv = bf2f(h[idx]);
  float hp = (bt & (TT-1)) ? bf2f(h[idx - CC]) : 0.f;
  xm[idx] = f2bf(hv + (hp - hv)*mu_x[c]);
}

// ---------------- single lerp-mix build: hm = h + (hprev-h)*(xx_i @ W_x2[i] + bias_i) -------
__global__ __launch_bounds__(128) void build_hm(const bf16* __restrict__ h, const bf16* __restrict__ xx,
        const float* __restrict__ W_x2i, const float* __restrict__ x_biasi, bf16* __restrict__ hm){
  int bt0 = blockIdx.x*16;
  int c = blockIdx.y*128 + threadIdx.x;
  float W[32];
  #pragma unroll
  for (int r=0;r<32;r++) W[r] = W_x2i[(size_t)r*CC + c];
  float bia = x_biasi[c];
  #pragma unroll 1
  for (int j=0;j<16;j++){
    int bt = bt0+j;
    float hv = bf2f(h[(size_t)bt*CC + c]);
    float hp = ((bt & (TT-1)) != 0) ? bf2f(h[(size_t)(bt-1)*CC + c]) : 0.f;
    const bf16* xr = xx + (size_t)bt*256;
    float acc = bia;
    #pragma unroll
    for (int r=0;r<32;r++) acc += bf2f(xr[r])*W[r];
    hm[(size_t)bt*CC + c] = f2bf(hv + (hp-hv)*acc);
  }
}

// ---------------- epilogue modes ----------------
enum {EP_BF16, EP_TANH_BF16, EP_NEGEXP_F32, EP_RES_F32, EP_RELU2_BF16, EP_SIG_BF16, EP_FINAL_F32};

// ---------------- m97-style 128x128 MFMA GEMM with global_load_lds staging -------------
template<int MODE>
__global__ __launch_bounds__(256) void gemm128(
    const bf16* __restrict__ A, const bf16* __restrict__ Bt, void* __restrict__ Out,
    int N, int K, const float* __restrict__ auxf, const bf16* __restrict__ auxb)
{
  __shared__ bf16 Al[128][32];
  __shared__ bf16 Bl[128][32];
  int tid = threadIdx.x;
  int nbk = N>>7;
  int q8 = gridDim.x>>3;
  int o = (blockIdx.x & 7)*q8 + (blockIdx.x>>3);
  int nb = o % nbk, mb = o / nbk;
  int m0 = mb*128, n0 = nb*128;
  int wv = tid>>6, ln = tid&63;
  int wr = wv>>1, wc = wv&1;
  f32x4 acc[4][4];
  #pragma unroll
  for (int i=0;i<4;i++) for (int j=0;j<4;j++){ f32x4 z={0.f,0.f,0.f,0.f}; acc[i][j]=z; }
  int r0 = tid>>2, k0 = (tid&3)*8;
  const int nkt = K>>5;
  for (int kt=0; kt<nkt; kt++){
    const bf16* ga = A  + (size_t)(m0+r0)*K + kt*32 + k0;
    const bf16* gb = Bt + (size_t)(n0+r0)*K + kt*32 + k0;
    gload16(ga,                 (char*)&Al[0][0] + tid*16);
    gload16(ga + (size_t)64*K,  (char*)&Al[0][0] + (tid+256)*16);
    gload16(gb,                 (char*)&Bl[0][0] + tid*16);
    gload16(gb + (size_t)64*K,  (char*)&Bl[0][0] + (tid+256)*16);
    __syncthreads();
    int ks = (ln>>4)*8;
    s16x8 af[4], bq[4];
    #pragma unroll
    for (int i=0;i<4;i++){
      af[i] = *(const s16x8*)&Al[wr*64 + i*16 + (ln&15)][ks];
      bq[i] = *(const s16x8*)&Bl[wc*64 + i*16 + (ln&15)][ks];
    }
    #pragma unroll
    for (int mi=0;mi<4;mi++)
      #pragma unroll
      for (int ni=0;ni<4;ni++)
        acc[mi][ni] = __builtin_amdgcn_mfma_f32_16x16x32_bf16(af[mi], bq[ni], acc[mi][ni], 0,0,0);
    __syncthreads();
  }
  #pragma unroll
  for (int mi=0;mi<4;mi++)
    #pragma unroll
    for (int ni=0;ni<4;ni++){
      int col = n0 + wc*64 + ni*16 + (ln&15);
      int rb  = m0 + wr*64 + mi*16 + (ln>>4)*4;
      #pragma unroll
      for (int j=0;j<4;j++){
        size_t idx = (size_t)(rb+j)*N + col;
        float val = acc[mi][ni][j];
        if constexpr(MODE==EP_BF16)           ((bf16*)Out)[idx] = f2bf(val);
        else if constexpr(MODE==EP_TANH_BF16) ((bf16*)Out)[idx] = f2bf(tanhf(val));
        else if constexpr(MODE==EP_RES_F32)   ((float*)Out)[idx] = auxf[idx] + val;
        else if constexpr(MODE==EP_RELU2_BF16){ float m = fmaxf(val,0.f); ((bf16*)Out)[idx] = f2bf(m*m); }
        else if constexpr(MODE==EP_SIG_BF16)  ((bf16*)Out)[idx] = f2bf(1.f/(1.f+expf(-val)));
        else if constexpr(MODE==EP_FINAL_F32) ((float*)Out)[idx] = auxf[idx] + bf2f(auxb[idx])*val;
      }
    }
}

// ---------------- small-N GEMM (used for W1 N=64 and W2 K=64) -------------
template<int MODE>
__global__ __launch_bounds__(256) void gemm_bf16(
    const bf16* __restrict__ A, const bf16* __restrict__ Bt, void* __restrict__ Out,
    int N, int K, const float* __restrict__ auxf, const bf16* __restrict__ auxb,
    const float* __restrict__ bias)
{
  __shared__ bf16 Al[128][40];
  __shared__ bf16 Bl[64][40];
  int tid = threadIdx.x;
  int m0 = blockIdx.x*128, n0 = blockIdx.y*64;
  int wv = tid>>6, ln = tid&63;
  f32x4 acc[2][4];
  #pragma unroll
  for(int f=0;f<2;f++) for(int c=0;c<4;c++){ f32x4 z = {0.f,0.f,0.f,0.f}; acc[f][c]=z; }
  const int nkt = K>>5;
  for (int kt=0; kt<nkt; kt++){
    __syncthreads();
    {
      int c0 = tid, c1 = tid+256;
      int r = c0>>2, ko=(c0&3)*8;
      *(uint4*)&Al[r][ko] = *(const uint4*)&A[(size_t)(m0+r)*K + kt*32 + ko];
      r = c1>>2; ko=(c1&3)*8;
      *(uint4*)&Al[r][ko] = *(const uint4*)&A[(size_t)(m0+r)*K + kt*32 + ko];
      r = tid>>2; ko=(tid&3)*8;
      *(uint4*)&Bl[r][ko] = *(const uint4*)&Bt[(size_t)(n0+r)*K + kt*32 + ko];
    }
    __syncthreads();
    int ks = (ln>>4)*8;
    s16x8 af0 = *(const s16x8*)&Al[wv*32 + (ln&15)][ks];
    s16x8 af1 = *(const s16x8*)&Al[wv*32 + 16 + (ln&15)][ks];
    #pragma unroll
    for (int c=0;c<4;c++){
      s16x8 bfr = *(const s16x8*)&Bl[c*16 + (ln&15)][ks];
      acc[0][c] = __builtin_amdgcn_mfma_f32_16x16x32_bf16(af0, bfr, acc[0][c], 0,0,0);
      acc[1][c] = __builtin_amdgcn_mfma_f32_16x16x32_bf16(af1, bfr, acc[1][c], 0,0,0);
    }
  }
  #pragma unroll
  for (int f=0; f<2; f++) for (int c=0;c<4;c++){
    int col = n0 + c*16 + (ln&15);
    int rbase = m0 + wv*32 + f*16 + (ln>>4)*4;
    #pragma unroll
    for (int j=0;j<4;j++){
      size_t idx = (size_t)(rbase+j)*N + col;
      float val = acc[f][c][j];
      if constexpr(MODE==EP_TANH_BF16)      ((bf16*)Out)[idx] = f2bf(tanhf(val));
      else if constexpr(MODE==EP_NEGEXP_F32){ float w = -expf(val + bias[col]); ((float*)Out)[idx] = fmaxf(w, -20.f); }
    }
  }
}

// ---------------- WKV6 segment scan (32-token chunks, NSUB=128) ----------------
// P1: 2 waves/block; wave owns 64 v-cols; lane = k. State S[64] fits VGPRs.
__global__ __launch_bounds__(128,4) void wkv_p1(const bf16* __restrict__ kbuf, const bf16* __restrict__ vbuf,
      const float* __restrict__ wd, bf16* __restrict__ Mseg, float* __restrict__ Dseg){
  int bhs = blockIdx.x; int bh = bhs>>7, sub = bhs&127;
  int b = bh>>2, h = bh&3;
  int tid = threadIdx.x, wv = tid>>6, ln = tid&63;
  __shared__ float vtile[16][132];
  int t0 = sub*SUB;
  size_t kqbase = ((size_t)b*TT + t0)*KD + h*64 + ln;
  float csum = 0.f;
  float S[64];
  #pragma unroll
  for (int v=0;v<64;v++) S[v]=0.f;
  float wnxt = wd[kqbase];
  unsigned short qnxt = ((const unsigned short*)kbuf)[kqbase];
  #pragma unroll 1
  for (int tile=0; tile<2; tile++){
    int tb = t0 + tile*16;
    __syncthreads();
    {
      int t = tid>>3, c = (tid&7)*16;
      const unsigned short* vg = (const unsigned short*)vbuf + ((size_t)b*TT + tb + t)*VD + h*128 + c;
      u16x8 a8 = *(const u16x8*)vg;
      u16x8 b8 = *(const u16x8*)(vg+8);
      #pragma unroll
      for (int e=0;e<8;e++){ vtile[t][c+e] = bfbits(a8[e]); vtile[t][c+8+e] = bfbits(b8[e]); }
    }
    __syncthreads();
    #pragma unroll 1
    for (int tt=0;tt<16;tt++){
      int lt = tile*16+tt;
      float wcur = wnxt; unsigned short qcur = qnxt;
      if (lt < SUB-1){
        size_t gi = kqbase + (size_t)(lt+1)*KD;
        wnxt = wd[gi]; qnxt = ((const unsigned short*)kbuf)[gi];
      }
      csum += wcur;
      float e = expf(wcur), qv = bfbits(qcur);
      #pragma unroll
      for (int v4=0;v4<16;v4++){
        float4 vvv = *(const float4*)&vtile[tt][wv*64 + v4*4];
        S[v4*4+0] = e*S[v4*4+0] + qv*vvv.x;
        S[v4*4+1] = e*S[v4*4+1] + qv*vvv.y;
        S[v4*4+2] = e*S[v4*4+2] + qv*vvv.z;
        S[v4*4+3] = e*S[v4*4+3] + qv*vvv.w;
      }
    }
  }
  unsigned short* M = (unsigned short*)Mseg + (size_t)bhs*8192 + (size_t)ln*128 + wv*64;
  #pragma unroll
  for (int v4=0; v4<16; v4++){
    ushort4 s4;
    s4.x = f2bfbits(S[v4*4+0]); s4.y = f2bfbits(S[v4*4+1]);
    s4.z = f2bfbits(S[v4*4+2]); s4.w = f2bfbits(S[v4*4+3]);
    *(ushort4*)&M[v4*4] = s4;
  }
  if (wv==0) Dseg[(size_t)bhs*64 + ln] = expf(csum);
}

// P2: sequential combine across sub-chunks, IN-PLACE bf16 (Mseg becomes Sstart)
__global__ __launch_bounds__(256) void wkv_p2(bf16* __restrict__ MS, const float* __restrict__ Dseg){
  int idx = blockIdx.x*256 + threadIdx.x;
  int bh = idx>>13; int k = (idx>>7)&63; int v = idx&127;
  bf16* p = MS + (size_t)bh*NSUB*8192 + k*128 + v;
  const float* d = Dseg + (size_t)bh*NSUB*64 + k;
  float S = 0.f;
  float m = bf2f(p[0]); float D = d[0];
  #pragma unroll 1
  for (int seg=0; seg<NSUB; seg++){
    float mN=0.f, DN=0.f;
    if (seg < NSUB-1){ mN = bf2f(p[(size_t)(seg+1)*8192]); DN = d[(seg+1)*64]; }
    p[(size_t)seg*8192] = f2bf(S);
    S = D*S + m;
    m = mN; D = DN;
  }
}

// P3: 2 waves/block; k-split (wave owns 32 k-slots); per-token LDS combine; fused GN+silu gate.
__global__ __launch_bounds__(128,4) void wkv_p3(const bf16* __restrict__ rbuf, const bf16* __restrict__ kbuf,
     const bf16* __restrict__ vbuf, const float* __restrict__ wd, const bf16* __restrict__ Sstart,
     const float* __restrict__ uu, const bf16* __restrict__ gg,
     const float* __restrict__ gn_w, const float* __restrict__ gn_b, bf16* __restrict__ gated){
  int bhs = blockIdx.x; int bh = bhs>>7, sub = bhs&127;
  int b = bh>>2, h = bh&3;
  int tid = threadIdx.x, kw = tid>>6, ln = tid&63;
  __shared__ float ew[8][68], qk[8][68], rr[8][68], bu[8];
  __shared__ unsigned short vtb[8][128];
  __shared__ float2 pp[2][2][64];
  float gnw0 = gn_w[h*128+ln], gnw1 = gn_w[h*128+64+ln];
  float gnb0 = gn_b[h*128+ln], gnb1 = gn_b[h*128+64+ln];
  float4 u4 = *(const float4*)&uu[h*64 + (tid&15)*4];
  float Sa[32], Sb[32];
  const unsigned short* Sst = (const unsigned short*)Sstart + (size_t)bhs*8192 + (size_t)kw*32*128;
  #pragma unroll
  for (int j=0;j<32;j++){ Sa[j]=bfbits(Sst[j*128+ln]); Sb[j]=bfbits(Sst[j*128+ln+64]); }
  int t0 = sub*SUB;
  #pragma unroll 1
  for (int tile=0; tile<4; tile++){
    int tb = t0 + tile*8;
    __syncthreads();
    int tq = tid>>4, c4 = (tid&15)*4;
    {
      float4 w4 = *(const float4*)&wd[((size_t)b*TT + tb + tq)*KD + h*64 + c4];
      ew[tq][c4+0]=expf(w4.x); ew[tq][c4+1]=expf(w4.y); ew[tq][c4+2]=expf(w4.z); ew[tq][c4+3]=expf(w4.w);
    }
    {
      size_t gi = ((size_t)b*TT + tb + tq)*KD + h*64 + c4;
      ushort4 k4 = *(const ushort4*)&((const unsigned short*)kbuf)[gi];
      ushort4 r4 = *(const ushort4*)&((const unsigned short*)rbuf)[gi];
      float part = 0.f;
      float q0=bfbits(k4.x),q1=bfbits(k4.y),q2=bfbits(k4.z),q3=bfbits(k4.w);
      float rv0=bfbits(r4.x),rv1=bfbits(r4.y),rv2=bfbits(r4.z),rv3=bfbits(r4.w);
      qk[tq][c4+0]=q0; qk[tq][c4+1]=q1; qk[tq][c4+2]=q2; qk[tq][c4+3]=q3;
      rr[tq][c4+0]=rv0; rr[tq][c4+1]=rv1; rr[tq][c4+2]=rv2; rr[tq][c4+3]=rv3;
      part = rv0*q0*u4.x + rv1*q1*u4.y + rv2*q2*u4.z + rv3*q3*u4.w;
      part += __shfl_xor(part,1,64); part += __shfl_xor(part,2,64);
      part += __shfl_xor(part,4,64); part += __shfl_xor(part,8,64);
      if ((tid&15)==0) bu[tq] = part;
    }
    {
      int c = (tid&15)*8;
      *(u16x8*)&vtb[tq][c] = *(const u16x8*)&((const unsigned short*)vbuf)[((size_t)b*TT + tb + tq)*VD + h*128 + c];
    }
    __syncthreads();
    #pragma unroll 1
    for (int t=0;t<8;t++){
      int slot = t&1;
      float va = bfbits(vtb[t][ln]), vb = bfbits(vtb[t][ln+64]);
      float oa=0.f, ob=0.f;
      #pragma unroll
      for (int k4g=0;k4g<8;k4g++){
        int kk = kw*32 + k4g*4;
        float4 e4 = *(const float4*)&ew[t][kk];
        float4 q4 = *(const float4*)&qk[t][kk];
        float4 r4 = *(const float4*)&rr[t][kk];
        int j = k4g*4;
        oa += r4.x*Sa[j+0]; ob += r4.x*Sb[j+0]; Sa[j+0]=e4.x*Sa[j+0]+q4.x*va; Sb[j+0]=e4.x*Sb[j+0]+q4.x*vb;
        oa += r4.y*Sa[j+1]; ob += r4.y*Sb[j+1]; Sa[j+1]=e4.y*Sa[j+1]+q4.y*va; Sb[j+1]=e4.y*Sb[j+1]+q4.y*vb;
        oa += r4.z*Sa[j+2]; ob += r4.z*Sb[j+2]; Sa[j+2]=e4.z*Sa[j+2]+q4.z*va; Sb[j+2]=e4.z*Sb[j+2]+q4.z*vb;
        oa += r4.w*Sa[j+3]; ob += r4.w*Sb[j+3]; Sa[j+3]=e4.w*Sa[j+3]+q4.w*va; Sb[j+3]=e4.w*Sb[j+3]+q4.w*vb;
      }
      pp[slot][kw][ln] = make_float2(oa, ob);
      __syncthreads();
      if (kw==0){
        float2 pA = pp[slot][0][ln], pB = pp[slot][1][ln];
        float bb = bu[t];
        float ooa = pA.x + pB.x + bb*va;
        float oob = pA.y + pB.y + bb*vb;
        float s = ooa+oob, ss = ooa*ooa+oob*oob;
        #pragma unroll
        for (int off=32; off; off>>=1){ s += __shfl_xor(s,off,64); ss += __shfl_xor(ss,off,64); }
        float mu = s*(1.f/128.f);
        float inv = rsqrtf(fmaxf(ss*(1.f/128.f) - mu*mu, 0.f) + 1e-5f);
        float xa = (ooa-mu)*inv*gnw0 + gnb0;
        float xb = (oob-mu)*inv*gnw1 + gnb1;
        size_t go = ((size_t)b*TT + tb + t)*VD + h*128;
        float ga = bf2f(gg[go+ln]), gb = bf2f(gg[go+ln+64]);
        xa *= ga/(1.f+expf(-ga));
        xb *= gb/(1.f+expf(-gb));
        gated[go+ln] = f2bf(xa);
        gated[go+ln+64] = f2bf(xb);
      }
    }
  }
}

// ---------------- FFN lerp inputs (bf16 in/out) ----------------
__global__ void build_ffn_in(const bf16* __restrict__ hn, const float* __restrict__ mu_k,
                             const float* __restrict__ mu_r, bf16* __restrict__ kin, bf16* __restrict__ rin){
  size_t idx = (size_t)blockIdx.x*256 + threadIdx.x;
  int c = (int)(idx & (CC-1));
  size_t bt = idx >> 9;
  float hv = bf2f(hn[idx]);
  float hp = (bt & (TT-1)) ? bf2f(hn[idx - CC]) : 0.f;
  float d = hp - hv;
  kin[idx] = f2bf(hv + d*mu_k[c]);
  rin[idx] = f2bf(hv + d*mu_r[c]);
}

extern "C" void kernel_launch(void* const* d_in, const int* in_sizes, int n_in,
                              void* d_out, int out_size, void* d_ws, size_t ws_size,
                              hipStream_t stream){
  (void)in_sizes; (void)n_in; (void)out_size;
  if (ws_size < WS_NEED) return;
  const float* x      = (const float*)d_in[0];
  const float* ln1w   = (const float*)d_in[1];
  const float* ln1b   = (const float*)d_in[2];
  const float* mu_x   = (const float*)d_in[3];
  const float* W_x1   = (const float*)d_in[4];
  const float* W_x2   = (const float*)d_in[5];
  const float* x_bias = (const float*)d_in[6];
  const float* W_r    = (const float*)d_in[7];
  const float* W_k    = (const float*)d_in[8];
  const float* W_v    = (const float*)d_in[9];
  const float* W_g    = (const float*)d_in[10];
  const float* W_w1   = (const float*)d_in[11];
  const float* W_w2   = (const float*)d_in[12];
  const float* b_w2   = (const float*)d_in[13];
  const float* u      = (const float*)d_in[14];
  const float* gn_w   = (const float*)d_in[15];
  const float* gn_b   = (const float*)d_in[16];
  const float* W_o    = (const float*)d_in[17];
  const float* ln2w   = (const float*)d_in[18];
  const float* ln2b   = (const float*)d_in[19];
  const float* mu_k   = (const float*)d_in[20];
  const float* W_key  = (const float*)d_in[21];
  const float* mu_r   = (const float*)d_in[22];
  const float* W_rec  = (const float*)d_in[23];
  const float* W_val  = (const float*)d_in[24];
  char* ws = (char*)d_ws;
  auto F  = [&](size_t off){ return (float*)(ws+off); };
  auto Bf = [&](size_t off){ return (bf16*)(ws+off); };
  float* h2 = (float*)d_out;        // attn-out residual lives in d_out
  bf16* Mseg = (bf16*)d_out;        // scan summaries alias d_out (dead before O-gemm)

  // fused weight conversions (9920 blocks)
  wconv_all<<<9920,256,0,stream>>>(W_x1,W_r,W_k,W_v,W_g,W_w1,W_w2,W_o,W_key,W_rec,W_val, ws);

  // ---- attention pre-projections ----
  ln_bf16<<<BT,256,0,stream>>>(x, ln1w, ln1b, Bf(OFF_H1));
  build_xm<<<BT*CC/256,256,0,stream>>>(Bf(OFF_H1), mu_x, Bf(OFF_HM));
  gemm128<EP_TANH_BF16><<<512,256,0,stream>>>(Bf(OFF_HM), Bf(WT_X1), Bf(OFF_XX), 256,512, nullptr,nullptr);

  for (int i=0;i<5;i++){
    build_hm<<<dim3(BT/16,4),128,0,stream>>>(Bf(OFF_H1), Bf(OFF_XX)+i*32, W_x2 + (size_t)i*32*CC, x_bias + i*CC, Bf(OFF_HM));
    if (i==0)      gemm128<EP_BF16><<<512,256,0,stream>>>(Bf(OFF_HM), Bf(WT_R), Bf(OFF_R), 256,512, nullptr,nullptr);
    else if (i==1){
      gemm_bf16<EP_TANH_BF16><<<dim3(BT/128,1),256,0,stream>>>(Bf(OFF_HM), Bf(WT_W1), Bf(OFF_W1T), 64,512, nullptr,nullptr,nullptr);
      gemm_bf16<EP_NEGEXP_F32><<<dim3(BT/128,4),256,0,stream>>>(Bf(OFF_W1T), Bf(WT_W2), F(OFF_WD), 256,64, nullptr,nullptr,b_w2);
    }
    else if (i==2) gemm128<EP_BF16><<<512,256,0,stream>>>(Bf(OFF_HM), Bf(WT_K), Bf(OFF_K), 256,512, nullptr,nullptr);
    else if (i==3) gemm128<EP_BF16><<<1024,256,0,stream>>>(Bf(OFF_HM), Bf(WT_V), Bf(OFF_V), 512,512, nullptr,nullptr);
    else           gemm128<EP_BF16><<<1024,256,0,stream>>>(Bf(OFF_HM), Bf(WT_G), Bf(OFF_G), 512,512, nullptr,nullptr);
  }

  // ---- WKV6 segment scan (SUB=32, NSUB=128); Mseg/Sstart in d_out ----
  wkv_p1<<<BB*4*NSUB,128,0,stream>>>(Bf(OFF_K), Bf(OFF_V), F(OFF_WD), Mseg, F(OFF_DSEG));
  wkv_p2<<<BB*4*8192/256,256,0,stream>>>(Mseg, F(OFF_DSEG));
  wkv_p3<<<BB*4*NSUB,128,0,stream>>>(Bf(OFF_R), Bf(OFF_K), Bf(OFF_V), F(OFF_WD), Mseg, u,
                                     Bf(OFF_G), gn_w, gn_b, Bf(OFF_H1));

  // ---- output projection + residual -> h2 (in d_out; overwrites Mseg) ----
  gemm128<EP_RES_F32><<<1024,256,0,stream>>>(Bf(OFF_H1), Bf(WT_O), h2, 512,512, x,nullptr);

  // ---- channel mixing (FFN) ----
  ln_bf16<<<BT,256,0,stream>>>(h2, ln2w, ln2b, Bf(OFF_HM));
  build_ffn_in<<<BT*CC/256,256,0,stream>>>(Bf(OFF_HM), mu_k, mu_r, Bf(OFF_R), Bf(OFF_V));
  gemm128<EP_RELU2_BF16><<<2048,256,0,stream>>>(Bf(OFF_R), Bf(WT_KEY), Bf(OFF_WD), 1024,512, nullptr,nullptr);
  gemm128<EP_SIG_BF16><<<1024,256,0,stream>>>(Bf(OFF_V), Bf(WT_REC), Bf(OFF_H1), 512,512, nullptr,nullptr);
  gemm128<EP_FINAL_F32><<<1024,256,0,stream>>>(Bf(OFF_WD), Bf(WT_VAL), h2, 512,1024, h2, Bf(OFF_H1));
}